// Round 1
// baseline (110.718 us; speedup 1.0000x reference)
//
#include <hip/hip_runtime.h>

// Problem: B=4, L=256, D=768, OUT=256
//   pj[b,j,o] = sum_d text[b,j,d] * weight[o, d]
//   pi[b,i,o] = sum_d text[b,i,d] * weight[o, 768+d]
//   out[b,i,j,o] = pi[b,i,o] + pj[b,j,o] + bias[o]
// out: 4*256*256*256 f32 = 256 MiB -> write-BW bound (~43 us floor).
//
// ws layout (floats):
//   WT  [768][512]      : WT[d][h*256+o] = weight[o][h*768+d]   (393216 floats)
//   P   [2][1024][256]  : P[0]=pj, P[1]=pi+bias                 (524288 floats)

#define DDIM 768
#define WT_FLOATS (768 * 512)
#define P_HALF (1024 * 256)

typedef float f4 __attribute__((ext_vector_type(4)));

// ---- tiled weight transpose: weight[256][1536] -> WT[768][512] ----
__global__ __launch_bounds__(256) void k_transpose(const float* __restrict__ W,
                                                   float* __restrict__ WT) {
    __shared__ float t[32][33];
    const int c0 = blockIdx.x * 32;   // 0..1535 (48 tiles; 768%32==0, no straddle)
    const int o0 = blockIdx.y * 32;   // 0..255  (8 tiles)
    const int tx = threadIdx.x & 31, ty = threadIdx.x >> 5;
#pragma unroll
    for (int yy = ty; yy < 32; yy += 8)
        t[yy][tx] = W[(size_t)(o0 + yy) * 1536 + c0 + tx];
    __syncthreads();
#pragma unroll
    for (int yy = ty; yy < 32; yy += 8) {
        int c = c0 + yy;
        int h = (c >= 768) ? 1 : 0;
        int d = c - h * 768;
        WT[(size_t)d * 512 + h * 256 + o0 + tx] = t[tx][yy];
    }
}

// ---- GEMV-style P computation: 8 rows per block, 256 o-threads ----
// grid (128, 2): x = row tile (m0 = 8*bx over B*L=1024 rows), y = half h
__global__ __launch_bounds__(256) void k_gemv(const float* __restrict__ text,
                                              const float* __restrict__ bias,
                                              const float* __restrict__ WT,
                                              float* __restrict__ P) {
    const int m0 = blockIdx.x * 8;
    const int h  = blockIdx.y;
    const int o  = threadIdx.x;
    float acc[8];
    const float binit = h ? bias[o] : 0.0f;   // fold bias into pi half
#pragma unroll
    for (int r = 0; r < 8; ++r) acc[r] = binit;
    const float* t0 = text + (size_t)m0 * DDIM;      // block-uniform rows
    const float* wt = WT + h * 256 + o;
#pragma unroll 4
    for (int d = 0; d < DDIM; ++d) {
        float w = wt[(size_t)d * 512];               // coalesced across o
#pragma unroll
        for (int r = 0; r < 8; ++r)
            acc[r] = fmaf(t0[(size_t)r * DDIM + d], w, acc[r]); // uniform -> s_load
    }
    float* p = P + (size_t)h * P_HALF + (size_t)m0 * 256 + o;
#pragma unroll
    for (int r = 0; r < 8; ++r) p[(size_t)r * 256] = acc[r];
}

// ---- broadcast add: out[r][j][o] = pi[r][o] + pj[b*256+j][o] ----
// grid 1024 (r = b*256+i), 256 threads; each thread: fixed o4, loops j
__global__ __launch_bounds__(256) void k_bcast(const float* __restrict__ P,
                                               float* __restrict__ out) {
    const int r  = blockIdx.x;
    const int b  = r >> 8;
    const int o4 = (threadIdx.x & 63) * 4;
    const int jg = threadIdx.x >> 6;
    const f4 pi4 = *(const f4*)(P + (size_t)P_HALF + (size_t)r * 256 + o4);
    const float* pjb = P + (size_t)b * 65536;        // pj[b*256 + j][o]
    float* outr = out + (size_t)r * 65536;
#pragma unroll 4
    for (int j = jg; j < 256; j += 4) {
        f4 pj4 = *(const f4*)(pjb + j * 256 + o4);   // L2-resident
        f4 v = pi4 + pj4;
        __builtin_nontemporal_store(v, (f4*)(outr + j * 256 + o4));
    }
}

extern "C" void kernel_launch(void* const* d_in, const int* in_sizes, int n_in,
                              void* d_out, int out_size, void* d_ws, size_t ws_size,
                              hipStream_t stream) {
    const float* text   = (const float*)d_in[0];   // [4][256][768]
    const float* weight = (const float*)d_in[1];   // [256][1536]
    const float* bias   = (const float*)d_in[2];   // [256]
    float* out = (float*)d_out;                    // [4][256][256][256]
    float* WT  = (float*)d_ws;                     // [768][512]
    float* P   = WT + WT_FLOATS;                   // [2][1024][256]

    k_transpose<<<dim3(48, 8), 256, 0, stream>>>(weight, WT);
    k_gemv<<<dim3(128, 2), 256, 0, stream>>>(text, bias, WT, P);
    k_bcast<<<1024, 256, 0, stream>>>(P, out);
}

// Round 2
// 76.731 us; speedup vs baseline: 1.4429x; 1.4429x over previous
//
#include <hip/hip_runtime.h>

// Problem: B=4, L=256, D=768, OUT=256
//   pj[b,j,o] = sum_d text[b,j,d] * weight[o, d]
//   pi[b,i,o] = sum_d text[b,i,d] * weight[o, 768+d]
//   out[b,i,j,o] = pi[b,i,o] + pj[b,j,o] + bias[o]
// out: 4*256*256*256 f32 = 268 MB -> write-BW bound (~41 us floor at fill's 6.6 TB/s).
//
// ws layout (floats):
//   WT  [768][512]      : WT[d][h*256+o] = weight[o][h*768+d]   (393216 floats)
//   P   [2][1024][256]  : P[0]=pj, P[1]=pi+bias                 (524288 floats)

#define DDIM 768
#define WT_FLOATS (768 * 512)
#define P_HALF (1024 * 256)

typedef float f4 __attribute__((ext_vector_type(4)));

// ---- tiled weight transpose: weight[256][1536] -> WT[768][512] ----
__global__ __launch_bounds__(256) void k_transpose(const float* __restrict__ W,
                                                   float* __restrict__ WT) {
    __shared__ float t[32][33];
    const int c0 = blockIdx.x * 32;   // 0..1535 (48 tiles; 768%32==0, no straddle)
    const int o0 = blockIdx.y * 32;   // 0..255  (8 tiles)
    const int tx = threadIdx.x & 31, ty = threadIdx.x >> 5;
#pragma unroll
    for (int yy = ty; yy < 32; yy += 8)
        t[yy][tx] = W[(size_t)(o0 + yy) * 1536 + c0 + tx];
    __syncthreads();
#pragma unroll
    for (int yy = ty; yy < 32; yy += 8) {
        int c = c0 + yy;
        int h = (c >= 768) ? 1 : 0;
        int d = c - h * 768;
        WT[(size_t)d * 512 + h * 256 + o0 + tx] = t[tx][yy];
    }
}

// ---- P computation: 8 rows/block, 4-way d-split, 1024 threads ----
// grid (128, 2): x = row tile (m0 = 8*bx over B*L=1024 rows), y = half h
// thread: o = tid&255, dg = tid>>8 handles d in [dg*192, dg*192+192)
__global__ __launch_bounds__(1024) void k_gemv(const float* __restrict__ text,
                                               const float* __restrict__ bias,
                                               const float* __restrict__ WT,
                                               float* __restrict__ P) {
    __shared__ float red[4][8][256];   // 32 KB
    const int m0 = blockIdx.x * 8;
    const int h  = blockIdx.y;
    const int o  = threadIdx.x & 255;
    const int dg = __builtin_amdgcn_readfirstlane(threadIdx.x >> 8); // wave-uniform
    float acc[8];
#pragma unroll
    for (int r = 0; r < 8; ++r) acc[r] = 0.0f;
    const float* t0 = text + (size_t)m0 * DDIM + dg * 192;   // block+wave-uniform rows
    const float* wt = WT + (size_t)(dg * 192) * 512 + h * 256 + o;
#pragma unroll 4
    for (int d = 0; d < 192; ++d) {
        float w = wt[(size_t)d * 512];                       // coalesced across o, L2-hit
#pragma unroll
        for (int r = 0; r < 8; ++r)
            acc[r] = fmaf(t0[(size_t)r * DDIM + d], w, acc[r]);  // scalar (uniform)
    }
#pragma unroll
    for (int r = 0; r < 8; ++r) red[dg][r][o] = acc[r];
    __syncthreads();
    // 2048 outputs (8 r x 256 o), 1024 threads -> 2 each
#pragma unroll
    for (int k = 0; k < 2; ++k) {
        int flat = k * 1024 + threadIdx.x;
        int r = flat >> 8, oo = flat & 255;
        float s = red[0][r][oo] + red[1][r][oo] + red[2][r][oo] + red[3][r][oo];
        if (h) s += bias[oo];                                // fold bias into pi half
        P[(size_t)h * P_HALF + (size_t)(m0 + r) * 256 + oo] = s;
    }
}

// ---- broadcast add: out[r][j][o] = pi[r][o] + pj[b*256+j][o] ----
// grid 1024 (r = b*256+i), 256 threads; each thread: fixed o4, loops j
__global__ __launch_bounds__(256) void k_bcast(const float* __restrict__ P,
                                               float* __restrict__ out) {
    const int r  = blockIdx.x;
    const int b  = r >> 8;
    const int o4 = (threadIdx.x & 63) * 4;
    const int jg = threadIdx.x >> 6;
    const f4 pi4 = *(const f4*)(P + (size_t)P_HALF + (size_t)r * 256 + o4);
    const float* pjb = P + (size_t)b * 65536;        // pj[b*256 + j][o]
    float* outr = out + (size_t)r * 65536;
#pragma unroll 8
    for (int j = jg; j < 256; j += 4) {
        f4 pj4 = *(const f4*)(pjb + j * 256 + o4);   // L2-resident
        f4 v = pi4 + pj4;
        __builtin_nontemporal_store(v, (f4*)(outr + j * 256 + o4));
    }
}

extern "C" void kernel_launch(void* const* d_in, const int* in_sizes, int n_in,
                              void* d_out, int out_size, void* d_ws, size_t ws_size,
                              hipStream_t stream) {
    const float* text   = (const float*)d_in[0];   // [4][256][768]
    const float* weight = (const float*)d_in[1];   // [256][1536]
    const float* bias   = (const float*)d_in[2];   // [256]
    float* out = (float*)d_out;                    // [4][256][256][256]
    float* WT  = (float*)d_ws;                     // [768][512]
    float* P   = WT + WT_FLOATS;                   // [2][1024][256]

    k_transpose<<<dim3(48, 8), 256, 0, stream>>>(weight, WT);
    k_gemv<<<dim3(128, 2), 1024, 0, stream>>>(text, bias, WT, P);
    k_bcast<<<1024, 256, 0, stream>>>(P, out);
}